// Round 8
// baseline (88.591 us; speedup 1.0000x reference)
//
#include <hip/hip_runtime.h>

#define B 4
#define T 256
#define S 512
#define H 512
#define BTS (B*T*S)       // 524288

// 2 * log2(e): projections are prescaled so exp2 replaces exp in tanh.
#define PRESCALE 2.8853900817779268f
#define LOG2E 1.4426950408889634f
#define QCLAMP 15.0f      // clamp exp2 arg: ab <= 2^30, den (4-way) <= 2^120

typedef unsigned short u16;
typedef __attribute__((ext_vector_type(8))) short bf16x8;   // 8 bf16 in 4 VGPRs
typedef __attribute__((ext_vector_type(4))) float f32x4;

#if __has_builtin(__builtin_amdgcn_exp2f)
#define EXP2(x) __builtin_amdgcn_exp2f(x)
#else
#define EXP2(x) exp2f(x)
#endif

__device__ __forceinline__ u16 f2bf(float x) {              // RNE fp32->bf16
    unsigned u = __float_as_uint(x);
    u = u + 0x7FFFu + ((u >> 16) & 1u);
    return (u16)(u >> 16);
}

// split 8 fp32 -> bf16 hi (truncated) + bf16 lo (RNE of residual).
// hi+lo reconstructs x to ~2^-16 relative.
__device__ __forceinline__ void split8(float4 f0, float4 f1, bf16x8& hi, bf16x8& lo) {
    float x[8] = {f0.x, f0.y, f0.z, f0.w, f1.x, f1.y, f1.z, f1.w};
    #pragma unroll
    for (int i = 0; i < 8; ++i) {
        unsigned u = __float_as_uint(x[i]);
        unsigned h = u & 0xFFFF0000u;
        hi[i] = (short)(h >> 16);
        lo[i] = (short)f2bf(x[i] - __uint_as_float(h));
    }
}

// ---------------------------------------------------------------------------
// K1: MFMA projection GEMM with fused fp32->bf16 hi/lo split (Markidis:
// hi*hi + hi*lo + lo*hi) and fused epilogue e = exp2(min((acc+bias)*PRESCALE,QCLAMP)).
//   q rows (mTile<16)  -> abuf[t][h] row-major
//   k rows (mTile>=16) -> bT4[b][h/4][s][4] (transposed store)
// Block: 64m x 64n tile, 4 waves (each 32x32 as 2x2 of 16x16), BK=64.
// LDS 16B-chunk XOR-swizzled (chunk ^= row&7) to kill 128B-stride conflicts.
// ---------------------------------------------------------------------------
__global__ __launch_bounds__(256) void mfma_proj(
    const float* __restrict__ dh, const float* __restrict__ enc,
    const float* __restrict__ W1, const float* __restrict__ W2,
    const float* __restrict__ b1, const float* __restrict__ b2,
    float* __restrict__ abuf, float* __restrict__ bT4)
{
    __shared__ u16 lds[4 * 4096];   // [mat: Ahi,Alo,Whi,Wlo][64 rows][64 k]

    const int tid   = threadIdx.x;
    const int lane  = tid & 63;
    const int w     = tid >> 6;
    const int n0    = blockIdx.x * 64;
    const int mTile = blockIdx.y;           // 0..47
    const int mbase = mTile * 64;
    const bool is_q = (mTile < 16);

    const float* Asrc = is_q ? dh : enc;
    const float* Wsrc = is_q ? W1 : W2;
    const int arow = is_q ? mbase : (mbase - 1024);

    const int wm = (w & 1) * 32;
    const int wn = (w >> 1) * 32;

    const int r0  = tid >> 3;               // staging row 0..31 (second: +32)
    const int kc0 = tid & 7;                // staging k-chunk

    f32x4 acc[2][2] = {};                   // [ms][ns]

    for (int kb = 0; kb < 8; ++kb) {
        const int k0 = kb * 64 + kc0 * 8;
        const size_t ga0 = (size_t)(arow + r0) * 512 + k0;
        const size_t ga1 = (size_t)(arow + r0 + 32) * 512 + k0;
        const size_t gw0 = (size_t)(n0 + r0) * 512 + k0;
        const size_t gw1 = (size_t)(n0 + r0 + 32) * 512 + k0;
        bf16x8 ah0, al0, ah1, al1, wh0, wl0, wh1, wl1;
        split8(*(const float4*)&Asrc[ga0], *(const float4*)&Asrc[ga0 + 4], ah0, al0);
        split8(*(const float4*)&Asrc[ga1], *(const float4*)&Asrc[ga1 + 4], ah1, al1);
        split8(*(const float4*)&Wsrc[gw0], *(const float4*)&Wsrc[gw0 + 4], wh0, wl0);
        split8(*(const float4*)&Wsrc[gw1], *(const float4*)&Wsrc[gw1 + 4], wh1, wl1);
        __syncthreads();
        const int sw  = (kc0 ^ (r0 & 7)) << 3;       // (r0+32)&7 == r0&7
        const int s0o = r0 * 64 + sw;
        const int s1o = (r0 + 32) * 64 + sw;
        *(bf16x8*)&lds[0 * 4096 + s0o] = ah0;  *(bf16x8*)&lds[0 * 4096 + s1o] = ah1;
        *(bf16x8*)&lds[1 * 4096 + s0o] = al0;  *(bf16x8*)&lds[1 * 4096 + s1o] = al1;
        *(bf16x8*)&lds[2 * 4096 + s0o] = wh0;  *(bf16x8*)&lds[2 * 4096 + s1o] = wh1;
        *(bf16x8*)&lds[3 * 4096 + s0o] = wl0;  *(bf16x8*)&lds[3 * 4096 + s1o] = wl1;
        __syncthreads();

        #pragma unroll
        for (int ks = 0; ks < 2; ++ks) {
            const int kg = ks * 4 + (lane >> 4);     // k-chunk 0..7
            bf16x8 amh[2], aml[2], bnh[2], bnl[2];
            #pragma unroll
            for (int ms = 0; ms < 2; ++ms) {
                const int row = wm + ms * 16 + (lane & 15);
                const int off = row * 64 + ((kg ^ (row & 7)) << 3);
                amh[ms] = *(const bf16x8*)&lds[0 * 4096 + off];
                aml[ms] = *(const bf16x8*)&lds[1 * 4096 + off];
            }
            #pragma unroll
            for (int ns = 0; ns < 2; ++ns) {
                const int row = wn + ns * 16 + (lane & 15);
                const int off = row * 64 + ((kg ^ (row & 7)) << 3);
                bnh[ns] = *(const bf16x8*)&lds[2 * 4096 + off];
                bnl[ns] = *(const bf16x8*)&lds[3 * 4096 + off];
            }
            #pragma unroll
            for (int ms = 0; ms < 2; ++ms)
                #pragma unroll
                for (int ns = 0; ns < 2; ++ns) {
                    acc[ms][ns] = __builtin_amdgcn_mfma_f32_16x16x32_bf16(amh[ms], bnh[ns], acc[ms][ns], 0, 0, 0);
                    acc[ms][ns] = __builtin_amdgcn_mfma_f32_16x16x32_bf16(amh[ms], bnl[ns], acc[ms][ns], 0, 0, 0);
                    acc[ms][ns] = __builtin_amdgcn_mfma_f32_16x16x32_bf16(aml[ms], bnh[ns], acc[ms][ns], 0, 0, 0);
                }
        }
    }

    // fused epilogue: bias + prescale + exp2, dual-layout store
    const float* bias = is_q ? b1 : b2;
    #pragma unroll
    for (int ns = 0; ns < 2; ++ns) {
        const int gn = n0 + wn + ns * 16 + (lane & 15);
        const float bv = bias[gn];
        #pragma unroll
        for (int ms = 0; ms < 2; ++ms) {
            #pragma unroll
            for (int r = 0; r < 4; ++r) {
                const int gm = mbase + wm + ms * 16 + (lane >> 4) * 4 + r;
                const float e = EXP2(fminf((acc[ms][ns][r] + bv) * PRESCALE, QCLAMP));
                if (is_q) {
                    abuf[(size_t)gm * 512 + gn] = e;
                } else {
                    const int srow = gm - 1024;
                    const int bb = srow >> 9, ss = srow & 511;
                    bT4[(((size_t)(bb * 128 + (gn >> 2)) * 512) + ss) * 4 + (gn & 3)] = e;
                }
            }
        }
    }
}

// ---------------------------------------------------------------------------
// K2: score partials.  score = sum_h V[h] - 2*sum_h V[h]/(a*b+1) + bV
// 4-way rcp batching: sum V_i/x_i = [(V0x1+V1x0)p23 + (V2x3+V3x2)p01] / (p01*p23)
// ---------------------------------------------------------------------------
__device__ __forceinline__ float quad_term(float4 qa, float4 kb, float4 v4, float acc) {
    float x0 = fmaf(qa.x, kb.x, 1.f);
    float x1 = fmaf(qa.y, kb.y, 1.f);
    float x2 = fmaf(qa.z, kb.z, 1.f);
    float x3 = fmaf(qa.w, kb.w, 1.f);
    float p01 = x0 * x1, p23 = x2 * x3;
    float n01 = fmaf(v4.y, x0, v4.x * x1);
    float n23 = fmaf(v4.w, x2, v4.z * x3);
    float num = fmaf(n23, p01, n01 * p23);
    float den = p01 * p23;
    return fmaf(num, __builtin_amdgcn_rcpf(den), acc);
}

__global__ __launch_bounds__(256) void score_kernel(
    const float* __restrict__ abuf, const float* __restrict__ bT4,
    const float* __restrict__ Vp, const float* __restrict__ bVp,
    float* __restrict__ spart)
{
    const int tid  = threadIdx.x;
    const int lane = tid & 63;
    const int w    = tid >> 6;
    const int b    = blockIdx.z >> 2;
    const int c    = blockIdx.z & 3;           // h-chunk
    const int t0   = blockIdx.y * 16 + w * 4;
    const int s0   = blockIdx.x * 64;
    const int h0   = c * 128;

    float pv = Vp[h0 + lane] + Vp[h0 + 64 + lane];
    #pragma unroll
    for (int off = 32; off; off >>= 1) pv += __shfl_xor(pv, off);
    if (c == 0) pv += bVp[0];

    const float* a0 = abuf + __builtin_amdgcn_readfirstlane((b * T + t0 + 0) * H);
    const float* a1 = abuf + __builtin_amdgcn_readfirstlane((b * T + t0 + 1) * H);
    const float* a2 = abuf + __builtin_amdgcn_readfirstlane((b * T + t0 + 2) * H);
    const float* a3 = abuf + __builtin_amdgcn_readfirstlane((b * T + t0 + 3) * H);

    const float4* bp = (const float4*)bT4 + (size_t)(b * 128 + (h0 >> 2)) * S + s0 + lane;

    float acc0 = 0.f, acc1 = 0.f, acc2 = 0.f, acc3 = 0.f;

    #pragma unroll 4
    for (int h4 = 0; h4 < 32; ++h4) {
        const int h = h0 + h4 * 4;
        float4 kb = bp[(size_t)h4 * S];
        float4 v4  = *(const float4*)&Vp[h];
        float4 qa0 = *(const float4*)&a0[h];
        float4 qa1 = *(const float4*)&a1[h];
        float4 qa2 = *(const float4*)&a2[h];
        float4 qa3 = *(const float4*)&a3[h];
        acc0 = quad_term(qa0, kb, v4, acc0);
        acc1 = quad_term(qa1, kb, v4, acc1);
        acc2 = quad_term(qa2, kb, v4, acc2);
        acc3 = quad_term(qa3, kb, v4, acc3);
    }

    float* out = spart + (size_t)c * BTS;
    const int base = (b * T + t0) * S + s0 + lane;
    out[base + 0 * S] = fmaf(-2.f, acc0, pv);
    out[base + 1 * S] = fmaf(-2.f, acc1, pv);
    out[base + 2 * S] = fmaf(-2.f, acc2, pv);
    out[base + 3 * S] = fmaf(-2.f, acc3, pv);
}

// ---------------------------------------------------------------------------
// K3: fused softmax + context.  Block = (64 h-chunk, 16 t, b); grid 512 blocks.
// Each block recomputes the 16-row softmax (8x redundant over h-chunks; spart
// is L2-resident) into LDS, then context GEMV.  at padded [16][516]: row bank
// offset 4 -> <=2-way conflict on at[tt][s] reads.
// ---------------------------------------------------------------------------
__global__ __launch_bounds__(256) void softmax_ctx(
    const float* __restrict__ spart, const float* __restrict__ enc,
    float* __restrict__ out)
{
    __shared__ float at[16][516];

    const int tid  = threadIdx.x;
    const int lane = tid & 63;
    const int w    = tid >> 6;
    const int h0   = blockIdx.x * 64;
    const int t0   = blockIdx.y * 16;
    const int b    = blockIdx.z;

    #pragma unroll
    for (int rr = 0; rr < 4; ++rr) {
        const int row = w * 4 + rr;                          // 0..15
        const size_t base = (size_t)(b * T + t0 + row) * S + lane * 4;

        float4 x0 = make_float4(0.f, 0.f, 0.f, 0.f);
        float4 x1 = make_float4(0.f, 0.f, 0.f, 0.f);
        #pragma unroll
        for (int c = 0; c < 4; ++c) {
            float4 u = *(const float4*)&spart[base + (size_t)c * BTS];
            float4 v = *(const float4*)&spart[base + (size_t)c * BTS + 256];
            x0.x += u.x; x0.y += u.y; x0.z += u.z; x0.w += u.w;
            x1.x += v.x; x1.y += v.y; x1.z += v.z; x1.w += v.w;
        }

        float m = fmaxf(fmaxf(fmaxf(x0.x, x0.y), fmaxf(x0.z, x0.w)),
                        fmaxf(fmaxf(x1.x, x1.y), fmaxf(x1.z, x1.w)));
        #pragma unroll
        for (int off = 32; off; off >>= 1) m = fmaxf(m, __shfl_xor(m, off));

        float4 e0, e1;
        e0.x = EXP2((x0.x - m) * LOG2E); e0.y = EXP2((x0.y - m) * LOG2E);
        e0.z = EXP2((x0.z - m) * LOG2E); e0.w = EXP2((x0.w - m) * LOG2E);
        e1.x = EXP2((x1.x - m) * LOG2E); e1.y = EXP2((x1.y - m) * LOG2E);
        e1.z = EXP2((x1.z - m) * LOG2E); e1.w = EXP2((x1.w - m) * LOG2E);

        float sum = e0.x + e0.y + e0.z + e0.w + e1.x + e1.y + e1.z + e1.w;
        #pragma unroll
        for (int off = 32; off; off >>= 1) sum += __shfl_xor(sum, off);
        const float inv = __builtin_amdgcn_rcpf(sum);

        e0.x *= inv; e0.y *= inv; e0.z *= inv; e0.w *= inv;
        e1.x *= inv; e1.y *= inv; e1.z *= inv; e1.w *= inv;
        *(float4*)&at[row][lane * 4]       = e0;
        *(float4*)&at[row][lane * 4 + 256] = e1;
    }
    __syncthreads();

    const int tt = tid >> 4;         // 0..15 (t within tile)
    const int tc = (tid & 15) * 4;   // h offset within 64-chunk

    float4 acc = make_float4(0.f, 0.f, 0.f, 0.f);
    #pragma unroll 8
    for (int s = 0; s < S; ++s) {
        const float a = at[tt][s];
        float4 e4 = *(const float4*)&enc[(size_t)(b * S + s) * H + h0 + tc];
        acc.x = fmaf(a, e4.x, acc.x);
        acc.y = fmaf(a, e4.y, acc.y);
        acc.z = fmaf(a, e4.z, acc.z);
        acc.w = fmaf(a, e4.w, acc.w);
    }

    *(float4*)&out[(size_t)(b * T + t0 + tt) * H + h0 + tc] = acc;
}

extern "C" void kernel_launch(void* const* d_in, const int* in_sizes, int n_in,
                              void* d_out, int out_size, void* d_ws, size_t ws_size,
                              hipStream_t stream) {
    const float* dh  = (const float*)d_in[0];
    const float* enc = (const float*)d_in[1];
    const float* W1  = (const float*)d_in[2];
    const float* b1  = (const float*)d_in[3];
    const float* W2  = (const float*)d_in[4];
    const float* b2  = (const float*)d_in[5];
    const float* V   = (const float*)d_in[6];
    const float* bV  = (const float*)d_in[7];

    float* abuf  = (float*)d_ws;                    // B*T*H = 2 MB
    float* bT4   = abuf + (size_t)B * T * H;        // B*S*H = 4 MB
    float* spart = bT4 + (size_t)B * S * H;         // 4*BTS = 8 MB

    dim3 blk(256);
    mfma_proj   <<<dim3(8, 48),     blk, 0, stream>>>(dh, enc, W1, W2, b1, b2, abuf, bT4);
    score_kernel<<<dim3(8, 16, 16), blk, 0, stream>>>(abuf, bT4, V, bV, spart);
    softmax_ctx <<<dim3(8, 16, 4),  blk, 0, stream>>>(spart, enc, (float*)d_out);
}

// Round 9
// 84.982 us; speedup vs baseline: 1.0425x; 1.0425x over previous
//
#include <hip/hip_runtime.h>

#define B 4
#define T 256
#define S 512
#define H 512
#define BTS (B*T*S)       // 524288

// 2 * log2(e): projections are prescaled so exp2 replaces exp in tanh.
#define PRESCALE 2.8853900817779268f
#define LOG2E 1.4426950408889634f
#define QCLAMP 15.0f      // clamp exp2 arg: ab <= 2^30, den (4-way) <= 2^120

typedef unsigned short u16;
typedef __attribute__((ext_vector_type(8))) short bf16x8;   // 8 bf16 in 4 VGPRs
typedef __attribute__((ext_vector_type(4))) float f32x4;

#if __has_builtin(__builtin_amdgcn_exp2f)
#define EXP2(x) __builtin_amdgcn_exp2f(x)
#else
#define EXP2(x) exp2f(x)
#endif

__device__ __forceinline__ u16 f2bf(float x) {              // RNE fp32->bf16
    unsigned u = __float_as_uint(x);
    u = u + 0x7FFFu + ((u >> 16) & 1u);
    return (u16)(u >> 16);
}

// split 8 fp32 -> bf16 hi (truncated) + bf16 lo (RNE of residual).
__device__ __forceinline__ void split8(float4 f0, float4 f1, bf16x8& hi, bf16x8& lo) {
    float x[8] = {f0.x, f0.y, f0.z, f0.w, f1.x, f1.y, f1.z, f1.w};
    #pragma unroll
    for (int i = 0; i < 8; ++i) {
        unsigned u = __float_as_uint(x[i]);
        unsigned h = u & 0xFFFF0000u;
        hi[i] = (short)(h >> 16);
        lo[i] = (short)f2bf(x[i] - __uint_as_float(h));
    }
}

// ---------------------------------------------------------------------------
// K1: MFMA projection GEMM with fused fp32->bf16 hi/lo split (Markidis) and
// fused epilogue e = exp2(min((acc+bias)*PRESCALE,QCLAMP)).
//   q rows (mTile<16)  -> abuf[t][h] row-major
//   k rows (mTile>=16) -> bT4[b][h/4][s][4] (transposed store)
// ---------------------------------------------------------------------------
__global__ __launch_bounds__(256) void mfma_proj(
    const float* __restrict__ dh, const float* __restrict__ enc,
    const float* __restrict__ W1, const float* __restrict__ W2,
    const float* __restrict__ b1, const float* __restrict__ b2,
    float* __restrict__ abuf, float* __restrict__ bT4)
{
    __shared__ u16 lds[4 * 4096];   // [mat: Ahi,Alo,Whi,Wlo][64 rows][64 k]

    const int tid   = threadIdx.x;
    const int lane  = tid & 63;
    const int w     = tid >> 6;
    const int n0    = blockIdx.x * 64;
    const int mTile = blockIdx.y;           // 0..47
    const int mbase = mTile * 64;
    const bool is_q = (mTile < 16);

    const float* Asrc = is_q ? dh : enc;
    const float* Wsrc = is_q ? W1 : W2;
    const int arow = is_q ? mbase : (mbase - 1024);

    const int wm = (w & 1) * 32;
    const int wn = (w >> 1) * 32;

    const int r0  = tid >> 3;               // staging row 0..31 (second: +32)
    const int kc0 = tid & 7;                // staging k-chunk

    f32x4 acc[2][2] = {};                   // [ms][ns]

    for (int kb = 0; kb < 8; ++kb) {
        const int k0 = kb * 64 + kc0 * 8;
        const size_t ga0 = (size_t)(arow + r0) * 512 + k0;
        const size_t ga1 = (size_t)(arow + r0 + 32) * 512 + k0;
        const size_t gw0 = (size_t)(n0 + r0) * 512 + k0;
        const size_t gw1 = (size_t)(n0 + r0 + 32) * 512 + k0;
        bf16x8 ah0, al0, ah1, al1, wh0, wl0, wh1, wl1;
        split8(*(const float4*)&Asrc[ga0], *(const float4*)&Asrc[ga0 + 4], ah0, al0);
        split8(*(const float4*)&Asrc[ga1], *(const float4*)&Asrc[ga1 + 4], ah1, al1);
        split8(*(const float4*)&Wsrc[gw0], *(const float4*)&Wsrc[gw0 + 4], wh0, wl0);
        split8(*(const float4*)&Wsrc[gw1], *(const float4*)&Wsrc[gw1 + 4], wh1, wl1);
        __syncthreads();
        const int sw  = (kc0 ^ (r0 & 7)) << 3;       // (r0+32)&7 == r0&7
        const int s0o = r0 * 64 + sw;
        const int s1o = (r0 + 32) * 64 + sw;
        *(bf16x8*)&lds[0 * 4096 + s0o] = ah0;  *(bf16x8*)&lds[0 * 4096 + s1o] = ah1;
        *(bf16x8*)&lds[1 * 4096 + s0o] = al0;  *(bf16x8*)&lds[1 * 4096 + s1o] = al1;
        *(bf16x8*)&lds[2 * 4096 + s0o] = wh0;  *(bf16x8*)&lds[2 * 4096 + s1o] = wh1;
        *(bf16x8*)&lds[3 * 4096 + s0o] = wl0;  *(bf16x8*)&lds[3 * 4096 + s1o] = wl1;
        __syncthreads();

        #pragma unroll
        for (int ks = 0; ks < 2; ++ks) {
            const int kg = ks * 4 + (lane >> 4);     // k-chunk 0..7
            bf16x8 amh[2], aml[2], bnh[2], bnl[2];
            #pragma unroll
            for (int ms = 0; ms < 2; ++ms) {
                const int row = wm + ms * 16 + (lane & 15);
                const int off = row * 64 + ((kg ^ (row & 7)) << 3);
                amh[ms] = *(const bf16x8*)&lds[0 * 4096 + off];
                aml[ms] = *(const bf16x8*)&lds[1 * 4096 + off];
            }
            #pragma unroll
            for (int ns = 0; ns < 2; ++ns) {
                const int row = wn + ns * 16 + (lane & 15);
                const int off = row * 64 + ((kg ^ (row & 7)) << 3);
                bnh[ns] = *(const bf16x8*)&lds[2 * 4096 + off];
                bnl[ns] = *(const bf16x8*)&lds[3 * 4096 + off];
            }
            #pragma unroll
            for (int ms = 0; ms < 2; ++ms)
                #pragma unroll
                for (int ns = 0; ns < 2; ++ns) {
                    acc[ms][ns] = __builtin_amdgcn_mfma_f32_16x16x32_bf16(amh[ms], bnh[ns], acc[ms][ns], 0, 0, 0);
                    acc[ms][ns] = __builtin_amdgcn_mfma_f32_16x16x32_bf16(amh[ms], bnl[ns], acc[ms][ns], 0, 0, 0);
                    acc[ms][ns] = __builtin_amdgcn_mfma_f32_16x16x32_bf16(aml[ms], bnh[ns], acc[ms][ns], 0, 0, 0);
                }
        }
    }

    const float* bias = is_q ? b1 : b2;
    #pragma unroll
    for (int ns = 0; ns < 2; ++ns) {
        const int gn = n0 + wn + ns * 16 + (lane & 15);
        const float bv = bias[gn];
        #pragma unroll
        for (int ms = 0; ms < 2; ++ms) {
            #pragma unroll
            for (int r = 0; r < 4; ++r) {
                const int gm = mbase + wm + ms * 16 + (lane >> 4) * 4 + r;
                const float e = EXP2(fminf((acc[ms][ns][r] + bv) * PRESCALE, QCLAMP));
                if (is_q) {
                    abuf[(size_t)gm * 512 + gn] = e;
                } else {
                    const int srow = gm - 1024;
                    const int bb = srow >> 9, ss = srow & 511;
                    bT4[(((size_t)(bb * 128 + (gn >> 2)) * 512) + ss) * 4 + (gn & 3)] = e;
                }
            }
        }
    }
}

// ---------------------------------------------------------------------------
// K2: score partials.  score = sum_h V[h] - 2*sum_h V[h]/(a*b+1) + bV
// 4-way rcp batching.
// ---------------------------------------------------------------------------
__device__ __forceinline__ float quad_term(float4 qa, float4 kb, float4 v4, float acc) {
    float x0 = fmaf(qa.x, kb.x, 1.f);
    float x1 = fmaf(qa.y, kb.y, 1.f);
    float x2 = fmaf(qa.z, kb.z, 1.f);
    float x3 = fmaf(qa.w, kb.w, 1.f);
    float p01 = x0 * x1, p23 = x2 * x3;
    float n01 = fmaf(v4.y, x0, v4.x * x1);
    float n23 = fmaf(v4.w, x2, v4.z * x3);
    float num = fmaf(n23, p01, n01 * p23);
    float den = p01 * p23;
    return fmaf(num, __builtin_amdgcn_rcpf(den), acc);
}

__global__ __launch_bounds__(256) void score_kernel(
    const float* __restrict__ abuf, const float* __restrict__ bT4,
    const float* __restrict__ Vp, const float* __restrict__ bVp,
    float* __restrict__ spart)
{
    const int tid  = threadIdx.x;
    const int lane = tid & 63;
    const int w    = tid >> 6;
    const int b    = blockIdx.z >> 2;
    const int c    = blockIdx.z & 3;           // h-chunk
    const int t0   = blockIdx.y * 16 + w * 4;
    const int s0   = blockIdx.x * 64;
    const int h0   = c * 128;

    float pv = Vp[h0 + lane] + Vp[h0 + 64 + lane];
    #pragma unroll
    for (int off = 32; off; off >>= 1) pv += __shfl_xor(pv, off);
    if (c == 0) pv += bVp[0];

    const float* a0 = abuf + __builtin_amdgcn_readfirstlane((b * T + t0 + 0) * H);
    const float* a1 = abuf + __builtin_amdgcn_readfirstlane((b * T + t0 + 1) * H);
    const float* a2 = abuf + __builtin_amdgcn_readfirstlane((b * T + t0 + 2) * H);
    const float* a3 = abuf + __builtin_amdgcn_readfirstlane((b * T + t0 + 3) * H);

    const float4* bp = (const float4*)bT4 + (size_t)(b * 128 + (h0 >> 2)) * S + s0 + lane;

    float acc0 = 0.f, acc1 = 0.f, acc2 = 0.f, acc3 = 0.f;

    #pragma unroll 4
    for (int h4 = 0; h4 < 32; ++h4) {
        const int h = h0 + h4 * 4;
        float4 kb = bp[(size_t)h4 * S];
        float4 v4  = *(const float4*)&Vp[h];
        float4 qa0 = *(const float4*)&a0[h];
        float4 qa1 = *(const float4*)&a1[h];
        float4 qa2 = *(const float4*)&a2[h];
        float4 qa3 = *(const float4*)&a3[h];
        acc0 = quad_term(qa0, kb, v4, acc0);
        acc1 = quad_term(qa1, kb, v4, acc1);
        acc2 = quad_term(qa2, kb, v4, acc2);
        acc3 = quad_term(qa3, kb, v4, acc3);
    }

    float* out = spart + (size_t)c * BTS;
    const int base = (b * T + t0) * S + s0 + lane;
    out[base + 0 * S] = fmaf(-2.f, acc0, pv);
    out[base + 1 * S] = fmaf(-2.f, acc1, pv);
    out[base + 2 * S] = fmaf(-2.f, acc2, pv);
    out[base + 3 * S] = fmaf(-2.f, acc3, pv);
}

// ---------------------------------------------------------------------------
// K3a: softmax. 8 rows per block (2 per wave). Sums 4 spart chunks once.
// 128 blocks.
// ---------------------------------------------------------------------------
__global__ __launch_bounds__(256) void softmax_k(
    const float* __restrict__ spart, float* __restrict__ attnb)
{
    const int lane = threadIdx.x & 63;
    const int w    = threadIdx.x >> 6;

    #pragma unroll
    for (int r = 0; r < 2; ++r) {
        const int row = blockIdx.x * 8 + w * 2 + r;
        const size_t base = (size_t)row * S + lane * 4;

        float4 x0 = make_float4(0.f, 0.f, 0.f, 0.f);
        float4 x1 = make_float4(0.f, 0.f, 0.f, 0.f);
        #pragma unroll
        for (int c = 0; c < 4; ++c) {
            float4 u = *(const float4*)&spart[base + (size_t)c * BTS];
            float4 v = *(const float4*)&spart[base + (size_t)c * BTS + 256];
            x0.x += u.x; x0.y += u.y; x0.z += u.z; x0.w += u.w;
            x1.x += v.x; x1.y += v.y; x1.z += v.z; x1.w += v.w;
        }

        float m = fmaxf(fmaxf(fmaxf(x0.x, x0.y), fmaxf(x0.z, x0.w)),
                        fmaxf(fmaxf(x1.x, x1.y), fmaxf(x1.z, x1.w)));
        #pragma unroll
        for (int off = 32; off; off >>= 1) m = fmaxf(m, __shfl_xor(m, off));

        float4 e0, e1;
        e0.x = EXP2((x0.x - m) * LOG2E); e0.y = EXP2((x0.y - m) * LOG2E);
        e0.z = EXP2((x0.z - m) * LOG2E); e0.w = EXP2((x0.w - m) * LOG2E);
        e1.x = EXP2((x1.x - m) * LOG2E); e1.y = EXP2((x1.y - m) * LOG2E);
        e1.z = EXP2((x1.z - m) * LOG2E); e1.w = EXP2((x1.w - m) * LOG2E);

        float sum = e0.x + e0.y + e0.z + e0.w + e1.x + e1.y + e1.z + e1.w;
        #pragma unroll
        for (int off = 32; off; off >>= 1) sum += __shfl_xor(sum, off);
        const float inv = __builtin_amdgcn_rcpf(sum);

        e0.x *= inv; e0.y *= inv; e0.z *= inv; e0.w *= inv;
        e1.x *= inv; e1.y *= inv; e1.z *= inv; e1.w *= inv;
        *(float4*)&attnb[base]       = e0;
        *(float4*)&attnb[base + 256] = e1;
    }
}

// ---------------------------------------------------------------------------
// K3b: context = attn @ enc.  Block = 8 t x 64 h, in-block 2-way s-split
// (each half integrates 256 s; partials combined via LDS).
// Grid (8 hc, 32 tt, 4 b) = 1024 blocks -> 4 blocks/CU, ~16 waves/CU.
// at padded [8][516]: 4 distinct broadcast rows land on different banks.
// ---------------------------------------------------------------------------
__global__ __launch_bounds__(256) void ctx_kernel(
    const float* __restrict__ attnb, const float* __restrict__ enc,
    float* __restrict__ out)
{
    __shared__ float at[8][516];
    __shared__ float part[8][16][4];   // [t][hg][4] partials from s-half 1

    const int tid = threadIdx.x;
    const int h0  = blockIdx.x * 64;
    const int t0  = blockIdx.y * 8;
    const int b   = blockIdx.z;

    // stage attn: 8 rows x 512 = 1024 float4; 256 threads x 4
    #pragma unroll
    for (int j = 0; j < 4; ++j) {
        const int fidx = j * 256 + tid;
        const int row  = fidx >> 7;
        const int col  = (fidx & 127) * 4;
        float4 v = *(const float4*)&attnb[(size_t)(b * T + t0 + row) * S + col];
        *(float4*)&at[row][col] = v;
    }
    __syncthreads();

    const int hg = tid & 15;          // h = h0 + hg*4
    const int tt = (tid >> 4) & 7;    // t row
    const int sh = tid >> 7;          // s-half 0/1
    const int sbase = sh * 256;

    float4 acc = make_float4(0.f, 0.f, 0.f, 0.f);
    #pragma unroll 8
    for (int si = 0; si < 256; ++si) {
        const int s = sbase + si;
        const float a = at[tt][s];
        float4 e4 = *(const float4*)&enc[(size_t)(b * S + s) * H + h0 + hg * 4];
        acc.x = fmaf(a, e4.x, acc.x);
        acc.y = fmaf(a, e4.y, acc.y);
        acc.z = fmaf(a, e4.z, acc.z);
        acc.w = fmaf(a, e4.w, acc.w);
    }

    if (sh == 1) *(float4*)&part[tt][hg][0] = acc;
    __syncthreads();
    if (sh == 0) {
        float4 p = *(const float4*)&part[tt][hg][0];
        acc.x += p.x; acc.y += p.y; acc.z += p.z; acc.w += p.w;
        *(float4*)&out[(size_t)(b * T + t0 + tt) * H + h0 + hg * 4] = acc;
    }
}

extern "C" void kernel_launch(void* const* d_in, const int* in_sizes, int n_in,
                              void* d_out, int out_size, void* d_ws, size_t ws_size,
                              hipStream_t stream) {
    const float* dh  = (const float*)d_in[0];
    const float* enc = (const float*)d_in[1];
    const float* W1  = (const float*)d_in[2];
    const float* b1  = (const float*)d_in[3];
    const float* W2  = (const float*)d_in[4];
    const float* b2  = (const float*)d_in[5];
    const float* V   = (const float*)d_in[6];
    const float* bV  = (const float*)d_in[7];

    float* abuf  = (float*)d_ws;                    // B*T*H = 2 MB
    float* bT4   = abuf + (size_t)B * T * H;        // B*S*H = 4 MB
    float* spart = bT4 + (size_t)B * S * H;         // 4*BTS = 8 MB
    float* attnb = spart + 4 * (size_t)BTS;         // B*T*S = 2 MB

    dim3 blk(256);
    mfma_proj   <<<dim3(8, 48),     blk, 0, stream>>>(dh, enc, W1, W2, b1, b2, abuf, bT4);
    score_kernel<<<dim3(8, 16, 16), blk, 0, stream>>>(abuf, bT4, V, bV, spart);
    softmax_k   <<<dim3(128),       blk, 0, stream>>>(spart, attnb);
    ctx_kernel  <<<dim3(8, 32, 4),  blk, 0, stream>>>(attnb, enc, (float*)d_out);
}

// Round 10
// 67.970 us; speedup vs baseline: 1.3034x; 1.2503x over previous
//
#include <hip/hip_runtime.h>

#define B 4
#define T 256
#define S 512
#define H 512
#define BTS (B*T*S)       // 524288

// 2 * log2(e): projections are prescaled so exp2 replaces exp in tanh.
#define PRESCALE 2.8853900817779268f
#define LOG2E 1.4426950408889634f
#define QCLAMP 15.0f      // clamp exp2 arg: ab <= 2^30, den (4-way) <= 2^120

typedef unsigned short u16;
typedef __attribute__((ext_vector_type(8))) short bf16x8;   // 8 bf16 in 4 VGPRs
typedef __attribute__((ext_vector_type(4))) float f32x4;

#if __has_builtin(__builtin_amdgcn_exp2f)
#define EXP2(x) __builtin_amdgcn_exp2f(x)
#else
#define EXP2(x) exp2f(x)
#endif

__device__ __forceinline__ u16 f2bf(float x) {              // RNE fp32->bf16
    unsigned u = __float_as_uint(x);
    u = u + 0x7FFFu + ((u >> 16) & 1u);
    return (u16)(u >> 16);
}

// split 8 fp32 -> bf16 hi (truncated) + bf16 lo (RNE of residual).
__device__ __forceinline__ void split8(float4 f0, float4 f1, bf16x8& hi, bf16x8& lo) {
    float x[8] = {f0.x, f0.y, f0.z, f0.w, f1.x, f1.y, f1.z, f1.w};
    #pragma unroll
    for (int i = 0; i < 8; ++i) {
        unsigned u = __float_as_uint(x[i]);
        unsigned h = u & 0xFFFF0000u;
        hi[i] = (short)(h >> 16);
        lo[i] = (short)f2bf(x[i] - __uint_as_float(h));
    }
}

// ---------------------------------------------------------------------------
// K1: MFMA projection GEMM with fused fp32->bf16 hi/lo split (Markidis) and
// fused epilogue e = exp2(min((acc+bias)*PRESCALE,QCLAMP)).
//   q rows (mTile<16)  -> abuf[t][h] row-major
//   k rows (mTile>=16) -> bT4[b][h/4][s][4] (transposed store)
// ---------------------------------------------------------------------------
__global__ __launch_bounds__(256) void mfma_proj(
    const float* __restrict__ dh, const float* __restrict__ enc,
    const float* __restrict__ W1, const float* __restrict__ W2,
    const float* __restrict__ b1, const float* __restrict__ b2,
    float* __restrict__ abuf, float* __restrict__ bT4)
{
    __shared__ u16 lds[4 * 4096];   // [mat: Ahi,Alo,Whi,Wlo][64 rows][64 k]

    const int tid   = threadIdx.x;
    const int lane  = tid & 63;
    const int w     = tid >> 6;
    const int n0    = blockIdx.x * 64;
    const int mTile = blockIdx.y;           // 0..47
    const int mbase = mTile * 64;
    const bool is_q = (mTile < 16);

    const float* Asrc = is_q ? dh : enc;
    const float* Wsrc = is_q ? W1 : W2;
    const int arow = is_q ? mbase : (mbase - 1024);

    const int wm = (w & 1) * 32;
    const int wn = (w >> 1) * 32;

    const int r0  = tid >> 3;               // staging row 0..31 (second: +32)
    const int kc0 = tid & 7;                // staging k-chunk

    f32x4 acc[2][2] = {};                   // [ms][ns]

    for (int kb = 0; kb < 8; ++kb) {
        const int k0 = kb * 64 + kc0 * 8;
        const size_t ga0 = (size_t)(arow + r0) * 512 + k0;
        const size_t ga1 = (size_t)(arow + r0 + 32) * 512 + k0;
        const size_t gw0 = (size_t)(n0 + r0) * 512 + k0;
        const size_t gw1 = (size_t)(n0 + r0 + 32) * 512 + k0;
        bf16x8 ah0, al0, ah1, al1, wh0, wl0, wh1, wl1;
        split8(*(const float4*)&Asrc[ga0], *(const float4*)&Asrc[ga0 + 4], ah0, al0);
        split8(*(const float4*)&Asrc[ga1], *(const float4*)&Asrc[ga1 + 4], ah1, al1);
        split8(*(const float4*)&Wsrc[gw0], *(const float4*)&Wsrc[gw0 + 4], wh0, wl0);
        split8(*(const float4*)&Wsrc[gw1], *(const float4*)&Wsrc[gw1 + 4], wh1, wl1);
        __syncthreads();
        const int sw  = (kc0 ^ (r0 & 7)) << 3;       // (r0+32)&7 == r0&7
        const int s0o = r0 * 64 + sw;
        const int s1o = (r0 + 32) * 64 + sw;
        *(bf16x8*)&lds[0 * 4096 + s0o] = ah0;  *(bf16x8*)&lds[0 * 4096 + s1o] = ah1;
        *(bf16x8*)&lds[1 * 4096 + s0o] = al0;  *(bf16x8*)&lds[1 * 4096 + s1o] = al1;
        *(bf16x8*)&lds[2 * 4096 + s0o] = wh0;  *(bf16x8*)&lds[2 * 4096 + s1o] = wh1;
        *(bf16x8*)&lds[3 * 4096 + s0o] = wl0;  *(bf16x8*)&lds[3 * 4096 + s1o] = wl1;
        __syncthreads();

        #pragma unroll
        for (int ks = 0; ks < 2; ++ks) {
            const int kg = ks * 4 + (lane >> 4);     // k-chunk 0..7
            bf16x8 amh[2], aml[2], bnh[2], bnl[2];
            #pragma unroll
            for (int ms = 0; ms < 2; ++ms) {
                const int row = wm + ms * 16 + (lane & 15);
                const int off = row * 64 + ((kg ^ (row & 7)) << 3);
                amh[ms] = *(const bf16x8*)&lds[0 * 4096 + off];
                aml[ms] = *(const bf16x8*)&lds[1 * 4096 + off];
            }
            #pragma unroll
            for (int ns = 0; ns < 2; ++ns) {
                const int row = wn + ns * 16 + (lane & 15);
                const int off = row * 64 + ((kg ^ (row & 7)) << 3);
                bnh[ns] = *(const bf16x8*)&lds[2 * 4096 + off];
                bnl[ns] = *(const bf16x8*)&lds[3 * 4096 + off];
            }
            #pragma unroll
            for (int ms = 0; ms < 2; ++ms)
                #pragma unroll
                for (int ns = 0; ns < 2; ++ns) {
                    acc[ms][ns] = __builtin_amdgcn_mfma_f32_16x16x32_bf16(amh[ms], bnh[ns], acc[ms][ns], 0, 0, 0);
                    acc[ms][ns] = __builtin_amdgcn_mfma_f32_16x16x32_bf16(amh[ms], bnl[ns], acc[ms][ns], 0, 0, 0);
                    acc[ms][ns] = __builtin_amdgcn_mfma_f32_16x16x32_bf16(aml[ms], bnh[ns], acc[ms][ns], 0, 0, 0);
                }
        }
    }

    const float* bias = is_q ? b1 : b2;
    #pragma unroll
    for (int ns = 0; ns < 2; ++ns) {
        const int gn = n0 + wn + ns * 16 + (lane & 15);
        const float bv = bias[gn];
        #pragma unroll
        for (int ms = 0; ms < 2; ++ms) {
            #pragma unroll
            for (int r = 0; r < 4; ++r) {
                const int gm = mbase + wm + ms * 16 + (lane >> 4) * 4 + r;
                const float e = EXP2(fminf((acc[ms][ns][r] + bv) * PRESCALE, QCLAMP));
                if (is_q) {
                    abuf[(size_t)gm * 512 + gn] = e;
                } else {
                    const int srow = gm - 1024;
                    const int bb = srow >> 9, ss = srow & 511;
                    bT4[(((size_t)(bb * 128 + (gn >> 2)) * 512) + ss) * 4 + (gn & 3)] = e;
                }
            }
        }
    }
}

// ---------------------------------------------------------------------------
// K2: score partials.  score = sum_h V[h] - 2*sum_h V[h]/(a*b+1) + bV
// 4-way rcp batching.
// ---------------------------------------------------------------------------
__device__ __forceinline__ float quad_term(float4 qa, float4 kb, float4 v4, float acc) {
    float x0 = fmaf(qa.x, kb.x, 1.f);
    float x1 = fmaf(qa.y, kb.y, 1.f);
    float x2 = fmaf(qa.z, kb.z, 1.f);
    float x3 = fmaf(qa.w, kb.w, 1.f);
    float p01 = x0 * x1, p23 = x2 * x3;
    float n01 = fmaf(v4.y, x0, v4.x * x1);
    float n23 = fmaf(v4.w, x2, v4.z * x3);
    float num = fmaf(n23, p01, n01 * p23);
    float den = p01 * p23;
    return fmaf(num, __builtin_amdgcn_rcpf(den), acc);
}

__global__ __launch_bounds__(256) void score_kernel(
    const float* __restrict__ abuf, const float* __restrict__ bT4,
    const float* __restrict__ Vp, const float* __restrict__ bVp,
    float* __restrict__ spart)
{
    const int tid  = threadIdx.x;
    const int lane = tid & 63;
    const int w    = tid >> 6;
    const int b    = blockIdx.z >> 2;
    const int c    = blockIdx.z & 3;           // h-chunk
    const int t0   = blockIdx.y * 16 + w * 4;
    const int s0   = blockIdx.x * 64;
    const int h0   = c * 128;

    float pv = Vp[h0 + lane] + Vp[h0 + 64 + lane];
    #pragma unroll
    for (int off = 32; off; off >>= 1) pv += __shfl_xor(pv, off);
    if (c == 0) pv += bVp[0];

    const float* a0 = abuf + __builtin_amdgcn_readfirstlane((b * T + t0 + 0) * H);
    const float* a1 = abuf + __builtin_amdgcn_readfirstlane((b * T + t0 + 1) * H);
    const float* a2 = abuf + __builtin_amdgcn_readfirstlane((b * T + t0 + 2) * H);
    const float* a3 = abuf + __builtin_amdgcn_readfirstlane((b * T + t0 + 3) * H);

    const float4* bp = (const float4*)bT4 + (size_t)(b * 128 + (h0 >> 2)) * S + s0 + lane;

    float acc0 = 0.f, acc1 = 0.f, acc2 = 0.f, acc3 = 0.f;

    #pragma unroll 4
    for (int h4 = 0; h4 < 32; ++h4) {
        const int h = h0 + h4 * 4;
        float4 kb = bp[(size_t)h4 * S];
        float4 v4  = *(const float4*)&Vp[h];
        float4 qa0 = *(const float4*)&a0[h];
        float4 qa1 = *(const float4*)&a1[h];
        float4 qa2 = *(const float4*)&a2[h];
        float4 qa3 = *(const float4*)&a3[h];
        acc0 = quad_term(qa0, kb, v4, acc0);
        acc1 = quad_term(qa1, kb, v4, acc1);
        acc2 = quad_term(qa2, kb, v4, acc2);
        acc3 = quad_term(qa3, kb, v4, acc3);
    }

    float* out = spart + (size_t)c * BTS;
    const int base = (b * T + t0) * S + s0 + lane;
    out[base + 0 * S] = fmaf(-2.f, acc0, pv);
    out[base + 1 * S] = fmaf(-2.f, acc1, pv);
    out[base + 2 * S] = fmaf(-2.f, acc2, pv);
    out[base + 3 * S] = fmaf(-2.f, acc3, pv);
}

// ---------------------------------------------------------------------------
// K3: fused softmax + t-register-blocked context.
// Block = (64 h, 8 t, b); grid (8, 32, 4) = 1024 blocks, 4/CU.
// Phase 1: softmax of the block's 8 full rows (8x redundant across h-chunks;
//          spart re-reads are L2-resident and cheap) -> at[8][520].
// Phase 2: thread = (sg, hg) keeps ALL 8 t accumulators in registers and
//          reads each enc float4 ONCE (kills the 8x L1 redundancy).
//          s order skewed by sg so the 4 concurrent LDS broadcast reads
//          per wave hit distinct banks.
// Phase 3: reduce 16 sg partials: shfl_xor(16,32) in-wave, LDS across waves.
// ---------------------------------------------------------------------------
__global__ __launch_bounds__(256) void softmax_ctx(
    const float* __restrict__ spart, const float* __restrict__ enc,
    float* __restrict__ out)
{
    __shared__ float at[8][520];
    __shared__ float part[4][8][16][4];   // [wave][tt][hg][4]

    const int tid = threadIdx.x;
    const int h0  = blockIdx.x * 64;
    const int t0  = blockIdx.y * 8;
    const int b   = blockIdx.z;

    // ---- phase 1: softmax (rows t0..t0+7, full S) ----
    {
        const int row = tid >> 5;            // 0..7
        const int c32 = tid & 31;            // 32 threads per row
        const size_t rbase = (size_t)(b * T + t0 + row) * S;

        float4 x[4];
        #pragma unroll
        for (int j = 0; j < 4; ++j) {
            const size_t off = rbase + j * 128 + c32 * 4;
            float4 u0 = *(const float4*)&spart[off];
            float4 u1 = *(const float4*)&spart[off + (size_t)BTS];
            float4 u2 = *(const float4*)&spart[off + 2 * (size_t)BTS];
            float4 u3 = *(const float4*)&spart[off + 3 * (size_t)BTS];
            x[j] = make_float4(u0.x + u1.x + u2.x + u3.x,
                               u0.y + u1.y + u2.y + u3.y,
                               u0.z + u1.z + u2.z + u3.z,
                               u0.w + u1.w + u2.w + u3.w);
        }

        float m = -1e30f;
        #pragma unroll
        for (int j = 0; j < 4; ++j)
            m = fmaxf(m, fmaxf(fmaxf(x[j].x, x[j].y), fmaxf(x[j].z, x[j].w)));
        #pragma unroll
        for (int off = 16; off; off >>= 1) m = fmaxf(m, __shfl_xor(m, off));

        float4 e[4];
        float sum = 0.f;
        #pragma unroll
        for (int j = 0; j < 4; ++j) {
            e[j].x = EXP2((x[j].x - m) * LOG2E);
            e[j].y = EXP2((x[j].y - m) * LOG2E);
            e[j].z = EXP2((x[j].z - m) * LOG2E);
            e[j].w = EXP2((x[j].w - m) * LOG2E);
            sum += e[j].x + e[j].y + e[j].z + e[j].w;
        }
        #pragma unroll
        for (int off = 16; off; off >>= 1) sum += __shfl_xor(sum, off);
        const float inv = __builtin_amdgcn_rcpf(sum);

        #pragma unroll
        for (int j = 0; j < 4; ++j) {
            float4 o = make_float4(e[j].x * inv, e[j].y * inv, e[j].z * inv, e[j].w * inv);
            *(float4*)&at[row][j * 128 + c32 * 4] = o;
        }
    }
    __syncthreads();

    // ---- phase 2: context with t-register blocking ----
    const int sg = tid >> 4;          // 0..15 (s-group)
    const int hg = tid & 15;          // h = h0 + hg*4
    const float* encb = enc + (size_t)b * S * H + h0 + hg * 4;

    float4 acc[8];
    #pragma unroll
    for (int tt = 0; tt < 8; ++tt) acc[tt] = make_float4(0.f, 0.f, 0.f, 0.f);

    #pragma unroll 4
    for (int si = 0; si < 32; ++si) {
        const int s = sg * 32 + ((si + sg) & 31);       // sg-skewed order
        float4 e4 = *(const float4*)&encb[(size_t)s * H];
        #pragma unroll
        for (int tt = 0; tt < 8; ++tt) {
            const float a = at[tt][s];
            acc[tt].x = fmaf(a, e4.x, acc[tt].x);
            acc[tt].y = fmaf(a, e4.y, acc[tt].y);
            acc[tt].z = fmaf(a, e4.z, acc[tt].z);
            acc[tt].w = fmaf(a, e4.w, acc[tt].w);
        }
    }

    // ---- phase 3: reduce over sg ----
    #pragma unroll
    for (int tt = 0; tt < 8; ++tt) {
        acc[tt].x += __shfl_xor(acc[tt].x, 16);
        acc[tt].y += __shfl_xor(acc[tt].y, 16);
        acc[tt].z += __shfl_xor(acc[tt].z, 16);
        acc[tt].w += __shfl_xor(acc[tt].w, 16);
        acc[tt].x += __shfl_xor(acc[tt].x, 32);
        acc[tt].y += __shfl_xor(acc[tt].y, 32);
        acc[tt].z += __shfl_xor(acc[tt].z, 32);
        acc[tt].w += __shfl_xor(acc[tt].w, 32);
    }
    const int wv   = tid >> 6;
    const int lane = tid & 63;
    if (lane < 16) {
        #pragma unroll
        for (int tt = 0; tt < 8; ++tt)
            *(float4*)&part[wv][tt][lane][0] = acc[tt];
    }
    __syncthreads();

    if (tid < 128) {
        const int tt  = tid >> 4;
        const int hgg = tid & 15;
        float4 p0 = *(const float4*)&part[0][tt][hgg][0];
        float4 p1 = *(const float4*)&part[1][tt][hgg][0];
        float4 p2 = *(const float4*)&part[2][tt][hgg][0];
        float4 p3 = *(const float4*)&part[3][tt][hgg][0];
        float4 r = make_float4(p0.x + p1.x + p2.x + p3.x,
                               p0.y + p1.y + p2.y + p3.y,
                               p0.z + p1.z + p2.z + p3.z,
                               p0.w + p1.w + p2.w + p3.w);
        *(float4*)&out[(size_t)(b * T + t0 + tt) * H + h0 + hgg * 4] = r;
    }
}

extern "C" void kernel_launch(void* const* d_in, const int* in_sizes, int n_in,
                              void* d_out, int out_size, void* d_ws, size_t ws_size,
                              hipStream_t stream) {
    const float* dh  = (const float*)d_in[0];
    const float* enc = (const float*)d_in[1];
    const float* W1  = (const float*)d_in[2];
    const float* b1  = (const float*)d_in[3];
    const float* W2  = (const float*)d_in[4];
    const float* b2  = (const float*)d_in[5];
    const float* V   = (const float*)d_in[6];
    const float* bV  = (const float*)d_in[7];

    float* abuf  = (float*)d_ws;                    // B*T*H = 2 MB
    float* bT4   = abuf + (size_t)B * T * H;        // B*S*H = 4 MB
    float* spart = bT4 + (size_t)B * S * H;         // 4*BTS = 8 MB

    dim3 blk(256);
    mfma_proj   <<<dim3(8, 48),     blk, 0, stream>>>(dh, enc, W1, W2, b1, b2, abuf, bT4);
    score_kernel<<<dim3(8, 16, 16), blk, 0, stream>>>(abuf, bT4, V, bV, spart);
    softmax_ctx <<<dim3(8, 32, 4),  blk, 0, stream>>>(spart, enc, (float*)d_out);
}